// Round 4
// baseline (526.950 us; speedup 1.0000x reference)
//
#include <hip/hip_runtime.h>
#include <math.h>

#define NB 16
#define LTOT 327
#define SDIM 256
#define ZD 64
#define ZROWS (NB * LTOT)        // 5232
#define ZBLOCKS (LTOT * 4)       // 1308: one block per (i, batch-quad)
#define ROWSZ ((size_t)LTOT * ZD)  // floats per (b,i) z row

typedef float vf4 __attribute__((ext_vector_type(4)));

__device__ __forceinline__ int regid(int x) {
    return (x >= 1) + (x >= 25) + (x >= 41) + (x >= 89) + (x >= 193) + (x >= 209) + (x >= 313);
}

__device__ __forceinline__ int pair_id(int i, int j, int ri, int rj) {
    if ((i == 0) && (j == 0)) return 0;
    if ((i == 0) || (j == 0)) return 1;
    if ((ri == 1) && (rj == 1)) {
        int d = i > j ? i - j : j - i;
        if (d == 1) return 2;
        if (d != 0) return 3;
        return 0;                 // cdr3 diagonal stays 0 (matches jnp.where order)
    }
    if ((ri == 1) || (rj == 1)) return 4;
    if (ri == rj) return 5 + ri - 2;
    int a = (ri < rj ? ri : rj) - 2;
    int c = (ri < rj ? rj : ri) - 2;
    return 11 + a * (11 - a) / 2 + (c - a - 1);   // N_COND=6
}

// blocks [0, ZBLOCKS): z, one block per (i, batch-quad) -> 4 batches x 327x64 floats
// blocks [ZBLOCKS, ZBLOCKS+ZROWS): s, one block per (b,l) row of 256 floats
__global__ __launch_bounds__(256) void fused_kernel(
    const float* __restrict__ s0, const float* __restrict__ s1,
    const float* __restrict__ s2, const float* __restrict__ s3,
    const float* __restrict__ s4, const float* __restrict__ s5,
    const float* __restrict__ s6,
    const float* __restrict__ seqW, const float* __restrict__ seqb,
    const float* __restrict__ posW, const float* __restrict__ posb,
    const float* __restrict__ p1W, const float* __restrict__ p1b,
    const float* __restrict__ p2W, const float* __restrict__ p2b,
    const float* __restrict__ ctok, const float* __restrict__ cw,
    const float* __restrict__ rw,
    float* __restrict__ out, float* __restrict__ outz)
{
    __shared__ __align__(16) float shbuf[32 * 68];
    int blk = blockIdx.x;
    int t = threadIdx.x;

    if (blk < ZBLOCKS) {
        // ---------------- z: batch-invariant row image, stored to 4 batches ----------------
        // 32-row lookup table: row[p] = [p1W[:,p/4]+p1b | p2W[:,p%4]+p2b]
        for (int idx = t; idx < 32 * 64; idx += 256) {
            int p = idx >> 6, c = idx & 63;
            float v = (c < 32) ? p1W[c * 8 + (p >> 2)] + p1b[c]
                               : p2W[(c - 32) * 4 + (p & 3)] + p2b[c - 32];
            shbuf[p * 68 + c] = v;
        }
        __syncthreads();

        int i  = blk >> 2;            // 0..326
        int bg = blk & 3;             // batch quad
        int ri = regid(i);
        int c4 = t & 15;              // which float4 of 16 in a 64-float row
        int jo = t >> 4;              // j offset within a 16-row stripe

        vf4* d0 = (vf4*)(outz + ((size_t)((bg * 4 + 0) * LTOT + i) * ROWSZ));
        vf4* d1 = (vf4*)(outz + ((size_t)((bg * 4 + 1) * LTOT + i) * ROWSZ));
        vf4* d2 = (vf4*)(outz + ((size_t)((bg * 4 + 2) * LTOT + i) * ROWSZ));
        vf4* d3 = (vf4*)(outz + ((size_t)((bg * 4 + 3) * LTOT + i) * ROWSZ));

        constexpr int ss_[8] = {0, 1, 25, 41, 89, 193, 209, 313};
        constexpr int se_[8] = {1, 25, 41, 89, 193, 209, 313, 327};

        #pragma unroll
        for (int s = 0; s < 8; s++) {
            const int js = ss_[s], je = se_[s];
            if (s == 1 && ri == 1) {
                // cdr3 row x cdr3 segment: p depends on |i-j| in {0(diag), 2(adj), 3}
                vf4 v0 = *(const vf4*)(shbuf + 0 * 68 + c4 * 4);
                vf4 v2 = *(const vf4*)(shbuf + 2 * 68 + c4 * 4);
                vf4 v3 = *(const vf4*)(shbuf + 3 * 68 + c4 * 4);
                for (int j = js + jo; j < je; j += 16) {
                    int d = i > j ? i - j : j - i;
                    vf4 v = (d == 0) ? v0 : ((d == 1) ? v2 : v3);
                    int off = j * 16 + c4;
                    d0[off] = v; d1[off] = v; d2[off] = v; d3[off] = v;
                }
            } else {
                int p = pair_id(i, js, ri, s);   // uniform over segment
                vf4 v = *(const vf4*)(shbuf + p * 68 + c4 * 4);
                for (int j = js + jo; j < je; j += 16) {
                    int off = j * 16 + c4;
                    d0[off] = v; d1[off] = v; d2[off] = v; d3[off] = v;
                }
            }
        }
    } else {
        // ---------------- s row: (b,l) -> 256 floats ----------------
        blk -= ZBLOCKS;
        int l = blk % LTOT;
        int b = blk / LTOT;
        int e = t;

        if (l == 0) {
            out[(size_t)blk * SDIM + e] = cw[0] * ctok[e];
            return;
        }
        constexpr int starts_[7] = {1, 25, 41, 89, 193, 209, 313};
        constexpr int lens_[7]   = {24, 16, 48, 104, 16, 104, 14};
        int k = (l >= 25) + (l >= 41) + (l >= 89) + (l >= 193) + (l >= 209) + (l >= 313);
        int pl = l - starts_[k];
        const float* sp;
        switch (k) {
            case 0: sp = s0; break; case 1: sp = s1; break; case 2: sp = s2; break;
            case 3: sp = s3; break; case 4: sp = s4; break; case 5: sp = s5; break;
            default: sp = s6;
        }
        float* sh_seq = shbuf;        // [0..20]
        float* sh_pe  = shbuf + 32;   // [32..95]
        if (e < 21) sh_seq[e] = sp[((size_t)b * lens_[k] + pl) * 21 + e];
        if (e < 64) {
            float scale = exp2f(-(float)e * (13.287712379549449f / 64.0f)); // 10000^(-e/64)
            float ang = (float)pl * scale;
            sh_pe[e] = (e & 1) ? cosf(ang) : sinf(ang);
        }
        __syncthreads();

        float se = seqb[e];
        const float* wrow = seqW + e * 21;
        #pragma unroll
        for (int d = 0; d < 21; d++) se = fmaf(sh_seq[d], wrow[d], se);

        float pe = posb[e];
        const float* pwrow = posW + e * 64;
        #pragma unroll 8
        for (int i2 = 0; i2 < 64; i2++) pe = fmaf(sh_pe[i2], pwrow[i2], pe);

        out[(size_t)blk * SDIM + e] = rw[2 * k] * se + rw[2 * k + 1] * pe;
    }
}

extern "C" void kernel_launch(void* const* d_in, const int* in_sizes, int n_in,
                              void* d_out, int out_size, void* d_ws, size_t ws_size,
                              hipStream_t stream) {
    const float* seq0 = (const float*)d_in[0];   // cdr3_xt (16,24,21)
    const float* seq1 = (const float*)d_in[1];   // pep
    const float* seq2 = (const float*)d_in[2];   // mhc
    const float* seq3 = (const float*)d_in[3];   // hv
    const float* seq4 = (const float*)d_in[4];   // hj
    const float* seq5 = (const float*)d_in[5];   // lv
    const float* seq6 = (const float*)d_in[6];   // lj
    const float* seqW = (const float*)d_in[7];   // (256,21)
    const float* seqb = (const float*)d_in[8];
    const float* posW = (const float*)d_in[9];   // (256,64)
    const float* posb = (const float*)d_in[10];
    const float* p1W  = (const float*)d_in[11];  // (32,8)
    const float* p1b  = (const float*)d_in[12];
    const float* p2W  = (const float*)d_in[13];  // (32,4)
    const float* p2b  = (const float*)d_in[14];
    const float* ctok = (const float*)d_in[15];  // (1,256)
    const float* cw   = (const float*)d_in[16];
    const float* rw   = (const float*)d_in[17];  // (7,2)

    float* out = (float*)d_out;
    float* outz = out + (size_t)NB * LTOT * SDIM;

    fused_kernel<<<ZBLOCKS + ZROWS, 256, 0, stream>>>(seq0, seq1, seq2, seq3, seq4, seq5, seq6,
                                                      seqW, seqb, posW, posb,
                                                      p1W, p1b, p2W, p2b,
                                                      ctok, cw, rw, out, outz);
}

// Round 5
// 525.092 us; speedup vs baseline: 1.0035x; 1.0035x over previous
//
#include <hip/hip_runtime.h>
#include <math.h>

#define NB 16
#define LTOT 327
#define SDIM 256
#define ZD 64
#define ZROWS (NB * LTOT)          // 5232
#define ROWSZ ((size_t)LTOT * ZD)  // floats per (b,i) z row

typedef float vf4 __attribute__((ext_vector_type(4)));

__device__ __forceinline__ int regid(int x) {
    return (x >= 1) + (x >= 25) + (x >= 41) + (x >= 89) + (x >= 193) + (x >= 209) + (x >= 313);
}

__device__ __forceinline__ int pair_id(int i, int j, int ri, int rj) {
    if ((i == 0) && (j == 0)) return 0;
    if ((i == 0) || (j == 0)) return 1;
    if ((ri == 1) && (rj == 1)) {
        int d = i > j ? i - j : j - i;
        if (d == 1) return 2;
        if (d != 0) return 3;
        return 0;                 // cdr3 diagonal stays 0 (matches jnp.where order)
    }
    if ((ri == 1) || (rj == 1)) return 4;
    if (ri == rj) return 5 + ri - 2;
    int a = (ri < rj ? ri : rj) - 2;
    int c = (ri < rj ? rj : ri) - 2;
    return 11 + a * (11 - a) / 2 + (c - a - 1);   // N_COND=6
}

// value of z[p][c4*4 .. c4*4+3] computed straight from the tiny weight arrays
__device__ __forceinline__ vf4 row_val(int p, int c4,
                                       const float* __restrict__ p1W, const float* __restrict__ p1b,
                                       const float* __restrict__ p2W, const float* __restrict__ p2b) {
    vf4 v;
    int c0 = c4 * 4;
    if (c0 < 32) {
        int col = p >> 2;
        #pragma unroll
        for (int q = 0; q < 4; q++) v[q] = p1W[(c0 + q) * 8 + col] + p1b[c0 + q];
    } else {
        int col = p & 3;
        #pragma unroll
        for (int q = 0; q < 4; q++) v[q] = p2W[(c0 + q - 32) * 4 + col] + p2b[c0 + q - 32];
    }
    return v;
}

// -------- z: (B,327,327,64). One block per (b,i) row. No LDS, no barriers. --------
__global__ __launch_bounds__(256) void z_kernel(
    const float* __restrict__ p1W, const float* __restrict__ p1b,
    const float* __restrict__ p2W, const float* __restrict__ p2b,
    float* __restrict__ outz)
{
    int blk = blockIdx.x;          // b*LTOT + i == z row index
    int t = threadIdx.x;
    int i = blk % LTOT;
    int ri = regid(i);
    int c4 = t & 15;               // which float4 of 16 in a 64-float row
    int jo = t >> 4;               // j offset within a 16-row stripe

    vf4* dst = (vf4*)(outz + (size_t)blk * ROWSZ);

    constexpr int ss_[8] = {0, 1, 25, 41, 89, 193, 209, 313};
    constexpr int se_[8] = {1, 25, 41, 89, 193, 209, 313, 327};

    #pragma unroll
    for (int s = 0; s < 8; s++) {
        const int js = ss_[s], je = se_[s];
        if (s == 1 && ri == 1) {
            // cdr3 row x cdr3 segment: p depends on |i-j| in {0(diag), 2(adj), 3}
            vf4 v0 = row_val(0, c4, p1W, p1b, p2W, p2b);
            vf4 v2 = row_val(2, c4, p1W, p1b, p2W, p2b);
            vf4 v3 = row_val(3, c4, p1W, p1b, p2W, p2b);
            for (int j = js + jo; j < je; j += 16) {
                int d = i > j ? i - j : j - i;
                vf4 v = (d == 0) ? v0 : ((d == 1) ? v2 : v3);
                dst[j * 16 + c4] = v;
            }
        } else {
            vf4 v = row_val(pair_id(i, js, ri, s), c4, p1W, p1b, p2W, p2b);
            #pragma unroll
            for (int j = js + jo; j < je; j += 16) {
                dst[j * 16 + c4] = v;              // pure streaming store
            }
        }
    }
}

// -------- pe: (327,256) b-invariant positional part, pre-scaled by region_w[k][1] --------
__global__ __launch_bounds__(256) void pe_kernel(
    const float* __restrict__ posW, const float* __restrict__ posb,
    const float* __restrict__ rw, float* __restrict__ pe_full)
{
    int l = blockIdx.x;
    int e = threadIdx.x;
    __shared__ float sh_pe[64];

    int k = (l >= 25) + (l >= 41) + (l >= 89) + (l >= 193) + (l >= 209) + (l >= 313);
    constexpr int starts_[7] = {1, 25, 41, 89, 193, 209, 313};
    int pl = (l == 0) ? 0 : (l - starts_[k]);
    if (e < 64) {
        float scale = exp2f(-(float)e * (13.287712379549449f / 64.0f)); // 10000^(-e/64)
        float ang = (float)pl * scale;
        sh_pe[e] = (e & 1) ? cosf(ang) : sinf(ang);
    }
    __syncthreads();

    float pe = posb[e];
    const float* pwrow = posW + e * 64;
    #pragma unroll 8
    for (int i2 = 0; i2 < 64; i2++) pe = fmaf(sh_pe[i2], pwrow[i2], pe);
    pe_full[(size_t)l * SDIM + e] = rw[2 * k + 1] * pe;
}

// -------- s: (B,327,256) --------
__global__ __launch_bounds__(256) void s_kernel2(
    const float* __restrict__ s0, const float* __restrict__ s1,
    const float* __restrict__ s2, const float* __restrict__ s3,
    const float* __restrict__ s4, const float* __restrict__ s5,
    const float* __restrict__ s6,
    const float* __restrict__ seqW, const float* __restrict__ seqb,
    const float* __restrict__ ctok, const float* __restrict__ cw,
    const float* __restrict__ rw, const float* __restrict__ pe_full,
    float* __restrict__ out)
{
    int blk = blockIdx.x;          // b*LTOT + l
    int l = blk % LTOT;
    int b = blk / LTOT;
    int e = threadIdx.x;

    if (l == 0) {
        out[(size_t)blk * SDIM + e] = cw[0] * ctok[e];
        return;
    }
    __shared__ float sh_seq[21];
    constexpr int starts_[7] = {1, 25, 41, 89, 193, 209, 313};
    constexpr int lens_[7]   = {24, 16, 48, 104, 16, 104, 14};
    int k = (l >= 25) + (l >= 41) + (l >= 89) + (l >= 193) + (l >= 209) + (l >= 313);
    int pl = l - starts_[k];
    const float* sp;
    switch (k) {
        case 0: sp = s0; break; case 1: sp = s1; break; case 2: sp = s2; break;
        case 3: sp = s3; break; case 4: sp = s4; break; case 5: sp = s5; break;
        default: sp = s6;
    }
    if (e < 21) sh_seq[e] = sp[((size_t)b * lens_[k] + pl) * 21 + e];
    __syncthreads();

    float se = seqb[e];
    const float* wrow = seqW + e * 21;
    #pragma unroll
    for (int d = 0; d < 21; d++) se = fmaf(sh_seq[d], wrow[d], se);

    out[(size_t)blk * SDIM + e] = rw[2 * k] * se + pe_full[(size_t)l * SDIM + e];
}

// -------- fallback single-pass s (if ws too small) --------
__global__ __launch_bounds__(256) void s_kernel(
    const float* __restrict__ s0, const float* __restrict__ s1,
    const float* __restrict__ s2, const float* __restrict__ s3,
    const float* __restrict__ s4, const float* __restrict__ s5,
    const float* __restrict__ s6,
    const float* __restrict__ seqW, const float* __restrict__ seqb,
    const float* __restrict__ posW, const float* __restrict__ posb,
    const float* __restrict__ ctok, const float* __restrict__ cw,
    const float* __restrict__ rw,
    float* __restrict__ out)
{
    int blk = blockIdx.x;
    int l = blk % LTOT;
    int b = blk / LTOT;
    int e = threadIdx.x;
    if (l == 0) { out[(size_t)blk * SDIM + e] = cw[0] * ctok[e]; return; }
    __shared__ float sh_seq[21];
    __shared__ float sh_pe[64];
    constexpr int starts_[7] = {1, 25, 41, 89, 193, 209, 313};
    constexpr int lens_[7]   = {24, 16, 48, 104, 16, 104, 14};
    int k = (l >= 25) + (l >= 41) + (l >= 89) + (l >= 193) + (l >= 209) + (l >= 313);
    int pl = l - starts_[k];
    const float* sp;
    switch (k) {
        case 0: sp = s0; break; case 1: sp = s1; break; case 2: sp = s2; break;
        case 3: sp = s3; break; case 4: sp = s4; break; case 5: sp = s5; break;
        default: sp = s6;
    }
    if (e < 21) sh_seq[e] = sp[((size_t)b * lens_[k] + pl) * 21 + e];
    if (e < 64) {
        float scale = exp2f(-(float)e * (13.287712379549449f / 64.0f));
        float ang = (float)pl * scale;
        sh_pe[e] = (e & 1) ? cosf(ang) : sinf(ang);
    }
    __syncthreads();
    float se = seqb[e];
    const float* wrow = seqW + e * 21;
    #pragma unroll
    for (int d = 0; d < 21; d++) se = fmaf(sh_seq[d], wrow[d], se);
    float pe = posb[e];
    const float* pwrow = posW + e * 64;
    #pragma unroll 8
    for (int i2 = 0; i2 < 64; i2++) pe = fmaf(sh_pe[i2], pwrow[i2], pe);
    out[(size_t)blk * SDIM + e] = rw[2 * k] * se + rw[2 * k + 1] * pe;
}

extern "C" void kernel_launch(void* const* d_in, const int* in_sizes, int n_in,
                              void* d_out, int out_size, void* d_ws, size_t ws_size,
                              hipStream_t stream) {
    const float* seq0 = (const float*)d_in[0];   // cdr3_xt (16,24,21)
    const float* seq1 = (const float*)d_in[1];   // pep
    const float* seq2 = (const float*)d_in[2];   // mhc
    const float* seq3 = (const float*)d_in[3];   // hv
    const float* seq4 = (const float*)d_in[4];   // hj
    const float* seq5 = (const float*)d_in[5];   // lv
    const float* seq6 = (const float*)d_in[6];   // lj
    const float* seqW = (const float*)d_in[7];   // (256,21)
    const float* seqb = (const float*)d_in[8];
    const float* posW = (const float*)d_in[9];   // (256,64)
    const float* posb = (const float*)d_in[10];
    const float* p1W  = (const float*)d_in[11];  // (32,8)
    const float* p1b  = (const float*)d_in[12];
    const float* p2W  = (const float*)d_in[13];  // (32,4)
    const float* p2b  = (const float*)d_in[14];
    const float* ctok = (const float*)d_in[15];  // (1,256)
    const float* cw   = (const float*)d_in[16];
    const float* rw   = (const float*)d_in[17];  // (7,2)

    float* out = (float*)d_out;
    float* outz = out + (size_t)NB * LTOT * SDIM;

    // z first: it owns ~99% of the bytes
    z_kernel<<<ZROWS, 256, 0, stream>>>(p1W, p1b, p2W, p2b, outz);

    if (ws_size >= (size_t)LTOT * SDIM * sizeof(float)) {
        float* pe_full = (float*)d_ws;
        pe_kernel<<<LTOT, 256, 0, stream>>>(posW, posb, rw, pe_full);
        s_kernel2<<<ZROWS, 256, 0, stream>>>(seq0, seq1, seq2, seq3, seq4, seq5, seq6,
                                             seqW, seqb, ctok, cw, rw, pe_full, out);
    } else {
        s_kernel<<<ZROWS, 256, 0, stream>>>(seq0, seq1, seq2, seq3, seq4, seq5, seq6,
                                            seqW, seqb, posW, posb, ctok, cw, rw, out);
    }
}

// Round 6
// 509.907 us; speedup vs baseline: 1.0334x; 1.0298x over previous
//
#include <hip/hip_runtime.h>
#include <math.h>

#define NB 16
#define LTOT 327
#define SDIM 256
#define ZD 64

// region starts (l-space; l=0 collapse token) and lengths
__device__ __constant__ int d_starts[7] = {1, 25, 41, 89, 193, 209, 313};
__device__ __constant__ int d_lens[7]   = {24, 16, 48, 104, 16, 104, 14};

// j-segment boundaries: [token][cdr3][pep][mhc][hv][hj][lv][lj]
__device__ __constant__ int seg_s[8] = {0, 1, 25, 41, 89, 193, 209, 313};
__device__ __constant__ int seg_e[8] = {1, 25, 41, 89, 193, 209, 313, 327};

__device__ __forceinline__ int regid(int x) {
    return (x >= 1) + (x >= 25) + (x >= 41) + (x >= 89) + (x >= 193) + (x >= 209) + (x >= 313);
}

__device__ __forceinline__ int pair_id(int i, int j, int ri, int rj) {
    if ((i == 0) && (j == 0)) return 0;
    if ((i == 0) || (j == 0)) return 1;
    if ((ri == 1) && (rj == 1)) {
        int d = i > j ? i - j : j - i;
        if (d == 1) return 2;
        if (d != 0) return 3;
        return 0;                 // cdr3 diagonal stays 0 (matches jnp.where order)
    }
    if ((ri == 1) || (rj == 1)) return 4;
    if (ri == rj) return 5 + ri - 2;
    int a = (ri < rj ? ri : rj) - 2;
    int c = (ri < rj ? rj : ri) - 2;
    return 11 + a * (11 - a) / 2 + (c - a - 1);   // N_COND=6
}

// -------- pe: (327, 256)  b-invariant positional part, pre-scaled by region_w[k][1]
__global__ __launch_bounds__(256) void pe_kernel(
    const float* __restrict__ posW, const float* __restrict__ posb,
    const float* __restrict__ rw, float* __restrict__ pe_full)
{
    int l = blockIdx.x;            // 0..326; l=0 unused downstream
    int e = threadIdx.x;
    __shared__ float sh_pe[64];

    int k = (l >= 25) + (l >= 41) + (l >= 89) + (l >= 193) + (l >= 209) + (l >= 313);
    int pl = (l == 0) ? 0 : (l - d_starts[k]);
    if (e < 64) {
        float scale = exp2f(-(float)e * (13.287712379549449f / 64.0f)); // 10000^(-e/64)
        float ang = (float)pl * scale;
        sh_pe[e] = (e & 1) ? cosf(ang) : sinf(ang);
    }
    __syncthreads();

    float pe = posb[e];
    const float* pwrow = posW + e * 64;
    #pragma unroll 8
    for (int i2 = 0; i2 < 64; i2++) pe = fmaf(sh_pe[i2], pwrow[i2], pe);
    pe_full[(size_t)l * SDIM + e] = rw[2 * k + 1] * pe;
}

// -------- s: (B, 327, 256)
__global__ __launch_bounds__(256) void s_kernel2(
    const float* __restrict__ s0, const float* __restrict__ s1,
    const float* __restrict__ s2, const float* __restrict__ s3,
    const float* __restrict__ s4, const float* __restrict__ s5,
    const float* __restrict__ s6,
    const float* __restrict__ seqW, const float* __restrict__ seqb,
    const float* __restrict__ ctok, const float* __restrict__ cw,
    const float* __restrict__ rw, const float* __restrict__ pe_full,
    float* __restrict__ out)
{
    int blk = blockIdx.x;          // b*LTOT + l
    int l = blk % LTOT;
    int b = blk / LTOT;
    int e = threadIdx.x;

    if (l == 0) {
        out[(size_t)blk * SDIM + e] = cw[0] * ctok[e];
        return;
    }
    __shared__ float sh_seq[21];
    int k = (l >= 25) + (l >= 41) + (l >= 89) + (l >= 193) + (l >= 209) + (l >= 313);
    int pl = l - d_starts[k];
    const float* sp;
    switch (k) {
        case 0: sp = s0; break; case 1: sp = s1; break; case 2: sp = s2; break;
        case 3: sp = s3; break; case 4: sp = s4; break; case 5: sp = s5; break;
        default: sp = s6;
    }
    if (e < 21) sh_seq[e] = sp[((size_t)b * d_lens[k] + pl) * 21 + e];
    __syncthreads();

    float se = seqb[e];
    const float* wrow = seqW + e * 21;
    #pragma unroll
    for (int d = 0; d < 21; d++) se = fmaf(sh_seq[d], wrow[d], se);

    out[(size_t)blk * SDIM + e] = rw[2 * k] * se + pe_full[(size_t)l * SDIM + e];
}

// -------- fallback single-pass s (if ws too small) --------
__global__ __launch_bounds__(256) void s_kernel(
    const float* __restrict__ s0, const float* __restrict__ s1,
    const float* __restrict__ s2, const float* __restrict__ s3,
    const float* __restrict__ s4, const float* __restrict__ s5,
    const float* __restrict__ s6,
    const float* __restrict__ seqW, const float* __restrict__ seqb,
    const float* __restrict__ posW, const float* __restrict__ posb,
    const float* __restrict__ ctok, const float* __restrict__ cw,
    const float* __restrict__ rw,
    float* __restrict__ out)
{
    int blk = blockIdx.x;
    int l = blk % LTOT;
    int b = blk / LTOT;
    int e = threadIdx.x;
    if (l == 0) { out[(size_t)blk * SDIM + e] = cw[0] * ctok[e]; return; }
    __shared__ float sh_seq[21];
    __shared__ float sh_pe[64];
    int k = (l >= 25) + (l >= 41) + (l >= 89) + (l >= 193) + (l >= 209) + (l >= 313);
    int pl = l - d_starts[k];
    const float* sp;
    switch (k) {
        case 0: sp = s0; break; case 1: sp = s1; break; case 2: sp = s2; break;
        case 3: sp = s3; break; case 4: sp = s4; break; case 5: sp = s5; break;
        default: sp = s6;
    }
    if (e < 21) sh_seq[e] = sp[((size_t)b * d_lens[k] + pl) * 21 + e];
    if (e < 64) {
        float scale = exp2f(-(float)e * (13.287712379549449f / 64.0f));
        float ang = (float)pl * scale;
        sh_pe[e] = (e & 1) ? cosf(ang) : sinf(ang);
    }
    __syncthreads();
    float se = seqb[e];
    const float* wrow = seqW + e * 21;
    #pragma unroll
    for (int d = 0; d < 21; d++) se = fmaf(sh_seq[d], wrow[d], se);
    float pe = posb[e];
    const float* pwrow = posW + e * 64;
    #pragma unroll 8
    for (int i2 = 0; i2 < 64; i2++) pe = fmaf(sh_pe[i2], pwrow[i2], pe);
    out[(size_t)blk * SDIM + e] = rw[2 * k] * se + rw[2 * k + 1] * pe;
}

// -------- z: (B, 327, 327, 64) — segment-hoisted pure-streaming stores --------
#define TSTRIDE 68   // 64 + 4 pad, keeps 16B alignment

__global__ __launch_bounds__(256) void z_kernel(
    const float* __restrict__ p1W, const float* __restrict__ p1b,
    const float* __restrict__ p2W, const float* __restrict__ p2b,
    float* __restrict__ outz)
{
    __shared__ __align__(16) float table[32 * TSTRIDE];
    int t = threadIdx.x;

    // 32-row lookup table: row[p] = [p1W[:,p/4]+p1b | p2W[:,p%4]+p2b]
    for (int idx = t; idx < 32 * 64; idx += 256) {
        int p = idx >> 6, c = idx & 63;
        float v;
        if (c < 32) v = p1W[c * 8 + (p >> 2)] + p1b[c];
        else        v = p2W[(c - 32) * 4 + (p & 3)] + p2b[c - 32];
        table[p * TSTRIDE + c] = v;
    }
    __syncthreads();

    int blk = blockIdx.x;          // b*LTOT + i
    int i = blk % LTOT;
    int ri = regid(i);
    int c4 = t & 15;               // which float4 of the 16 in a 64-float row
    int jo = t >> 4;               // j offset within a 16-row stripe

    float4* dst = (float4*)(outz + (size_t)blk * (LTOT * ZD));

    #pragma unroll
    for (int s = 0; s < 8; s++) {
        int js = seg_s[s], je = seg_e[s];
        if (ri == 1 && s == 1) {
            // cdr3 row × cdr3 segment: p varies with |i-j| in {0(diag),2(adj),3}
            float4 v0 = *(const float4*)(table + 0 * TSTRIDE + c4 * 4);
            float4 v2 = *(const float4*)(table + 2 * TSTRIDE + c4 * 4);
            float4 v3 = *(const float4*)(table + 3 * TSTRIDE + c4 * 4);
            for (int j = js + jo; j < je; j += 16) {
                int d = i > j ? i - j : j - i;
                float4 v = (d == 0) ? v0 : ((d == 1) ? v2 : v3);
                dst[j * 16 + c4] = v;
            }
        } else {
            int p = pair_id(i, js, ri, regid(js));   // uniform over the segment
            float4 v = *(const float4*)(table + p * TSTRIDE + c4 * 4);
            for (int j = js + jo; j < je; j += 16) {
                dst[j * 16 + c4] = v;                // pure streaming store
            }
        }
    }
}

extern "C" void kernel_launch(void* const* d_in, const int* in_sizes, int n_in,
                              void* d_out, int out_size, void* d_ws, size_t ws_size,
                              hipStream_t stream) {
    const float* seq0 = (const float*)d_in[0];
    const float* seq1 = (const float*)d_in[1];
    const float* seq2 = (const float*)d_in[2];
    const float* seq3 = (const float*)d_in[3];
    const float* seq4 = (const float*)d_in[4];
    const float* seq5 = (const float*)d_in[5];
    const float* seq6 = (const float*)d_in[6];
    const float* seqW = (const float*)d_in[7];
    const float* seqb = (const float*)d_in[8];
    const float* posW = (const float*)d_in[9];
    const float* posb = (const float*)d_in[10];
    const float* p1W  = (const float*)d_in[11];
    const float* p1b  = (const float*)d_in[12];
    const float* p2W  = (const float*)d_in[13];
    const float* p2b  = (const float*)d_in[14];
    const float* ctok = (const float*)d_in[15];
    const float* cw   = (const float*)d_in[16];
    const float* rw   = (const float*)d_in[17];

    float* out = (float*)d_out;
    float* outz = out + (size_t)NB * LTOT * SDIM;

    // z first: it's the big one; let it own the machine immediately
    z_kernel<<<NB * LTOT, 256, 0, stream>>>(p1W, p1b, p2W, p2b, outz);

    if (ws_size >= (size_t)LTOT * SDIM * sizeof(float)) {
        float* pe_full = (float*)d_ws;
        pe_kernel<<<LTOT, 256, 0, stream>>>(posW, posb, rw, pe_full);
        s_kernel2<<<NB * LTOT, 256, 0, stream>>>(seq0, seq1, seq2, seq3, seq4, seq5, seq6,
                                                 seqW, seqb, ctok, cw, rw, pe_full, out);
    } else {
        s_kernel<<<NB * LTOT, 256, 0, stream>>>(seq0, seq1, seq2, seq3, seq4, seq5, seq6,
                                                seqW, seqb, posW, posb, ctok, cw, rw, out);
    }
}